// Round 3
// baseline (389.230 us; speedup 1.0000x reference)
//
#include <hip/hip_runtime.h>

// SGIntoKGPool: out[b,m,c] = (sum_n adj[b,n,m] * x[b,c,n]) / max(sum_n adj[b,n,m], 1)
// fp32 in / fp32 out. Internal: bf16 MFMA 16x16x32, f32 accumulation; degrees exact fp32.
//
// R3 structure (vs R2's 378 us @ 1 block/CU, 2 barrier-drains/iter):
//  - grid 1024 = 8 bz x 64 m-blocks (BM=32) x 2 N-halves -> 4 independent
//    workgroups/CU so barrier vmcnt(0) drains interleave across blocks.
//  - double-buffered LDS tile -> ONE __syncthreads per K-iter.
//  - x pre-converted to bf16 in ws (kernel 1); halves B traffic, no pkbf in hot loop.
//  - N-halves write numerator/degree partials to ws; finalize kernel combines
//    + normalizes (no atomics, no zero-init needed).
//
// LDS swizzle (per 64n x 32m tile, bf16-packed pairs of n per dword):
//   element (m, nl) -> dword 36*m + 4*((nl>>3) ^ ((m>>2)&7)) + ((nl&7)>>1), half nl&1
//   row stride 36 dw + 16B-XOR: writes exactly 2-way banked (free), ds_read_b128
//   A-fragments exactly 8 lanes per 16B bank-group (conflict-free). Enumerated by hand.

typedef short bf16x8 __attribute__((ext_vector_type(8)));
typedef float f32x4 __attribute__((ext_vector_type(4)));

#define BZc 8
#define Cc 64
#define Nc 4096
#define Mc 2048
#define BMc 32
#define BKc 64
#define NSPLIT 2
#define NSc (Nc / NSPLIT)       // 2048
#define KITERS (NSc / BKc)      // 32
#define SDW 36                  // adjT row stride in dwords
#define TILE_DW (BMc * SDW)     // 1152 dwords per buffer

// ws layout (bytes):
//   X  [0, 4MB)          : x as bf16, (bz, c, n) = 8*64*4096 * 2B
//   P  [4MB, 20MB)       : numerator partials, [ns][bz*2048+m][c] fp32, 2 * 2^20 floats
//   D  [20MB, 20MB+128K) : degree partials, [ns][bz*2048+m] fp32
#define WS_X_BYTES   (BZc * Cc * Nc * 2)            // 4 MB
#define WS_P_FLOATS  (BZc * Mc * Cc)                // 2^20 per ns
#define WS_P_OFF     (WS_X_BYTES / 4)               // float offset of P
#define WS_D_OFF     (WS_P_OFF + NSPLIT * WS_P_FLOATS)
#define WS_D_FLOATS  (BZc * Mc)                     // 16384 per ns

// pack two fp32 -> dword, low16 = bf16(a), high16 = bf16(b); +0x8000 round-to-nearest
__device__ __forceinline__ unsigned int pkbf(float a, float b) {
  unsigned int ua = __float_as_uint(a) + 0x8000u;
  unsigned int ub = __float_as_uint(b) + 0x8000u;
  return (ua >> 16) | (ub & 0xffff0000u);
}

// ---- kernel 1: x fp32 -> bf16 into ws.X ----
__global__ __launch_bounds__(256) void xcvt_kernel(const float* __restrict__ x,
                                                   unsigned int* __restrict__ xb) {
  const int i = (blockIdx.x * 256 + threadIdx.x) * 8;   // element index
  float4 a = *(const float4*)(x + i);
  float4 b = *(const float4*)(x + i + 4);
  uint4 o = make_uint4(pkbf(a.x, a.y), pkbf(a.z, a.w),
                       pkbf(b.x, b.y), pkbf(b.z, b.w));
  *(uint4*)(xb + (i >> 1)) = o;
}

// ---- kernel 2: main GEMM over one N-half, writes partials ----
__global__ __launch_bounds__(256) void sgkg_main(
    const unsigned int* __restrict__ xbw,   // ws.X (bf16 pairs)
    const float* __restrict__ adj,          // (BZ, N, M) fp32
    float* __restrict__ P,                  // ws.P
    float* __restrict__ D)                  // ws.D
{
  __shared__ unsigned int adjT[2][TILE_DW];  // 9216 B
  __shared__ float degs[BMc];

  const int t = threadIdx.x;
  const int l = t & 63;
  const int w = t >> 6;                      // 4 waves

  const int bz     = blockIdx.x >> 7;        // 128 blocks per bz
  const int mb     = (blockIdx.x >> 1) & 63;
  const int ns     = blockIdx.x & 1;
  const int m_base = mb * BMc;
  const int n_base = ns * NSc;

  // ---- staging mapping: mg = 4-m group (0..7), p = n-row pair (0..31) ----
  const int mg  = l & 7;
  const int p   = (w << 3) | (l >> 3);
  const int sm0 = mg << 2;

  const float* aptr =
      adj + (size_t)bz * Nc * Mc + (size_t)(n_base + 2 * p) * Mc + (m_base + sm0);
  // write base dword (j-th write -> wb + j*SDW, row m = sm0+j, pi = mg)
  const int wb = SDW * sm0 + (((p >> 2) ^ mg) << 2) + (p & 3);

  // ---- compute mapping: wave covers c-tile c_b, both m-tiles ----
  const int c_b = w << 4;
  const int l15 = l & 15;
  const int l4  = l >> 4;

  // B-fragment uint4 base in ws.X: row c = c_b+l15; frag = 16B of 8 consecutive n
  const uint4* xq = (const uint4*)xbw +
      (size_t)(bz * Cc + c_b + l15) * (Nc / 8) + (n_base >> 3) + l4;

  // A-fragment LDS dword offsets per (m-tile, k-step)
  int aaddr[2][2];
#pragma unroll
  for (int tm = 0; tm < 2; ++tm) {
    const int m  = tm * 16 + l15;
    const int pi = (m >> 2) & 7;
    aaddr[tm][0] = SDW * m + ((l4 ^ pi) << 2);
    aaddr[tm][1] = SDW * m + (((4 + l4) ^ pi) << 2);
  }

  if (t < BMc) degs[t] = 0.0f;

  f32x4 acc0 = {0.f, 0.f, 0.f, 0.f};
  f32x4 acc1 = {0.f, 0.f, 0.f, 0.f};
  float dacc0 = 0.f, dacc1 = 0.f, dacc2 = 0.f, dacc3 = 0.f;

  // prefetch tile 0 (2 n-rows x 4 m fp32 per thread)
  float4 r0 = *(const float4*)aptr;
  float4 r1 = *(const float4*)(aptr + Mc);

  for (int it = 0; it < KITERS; ++it) {
    unsigned int* buf = adjT[it & 1];

    // ---- stage transposed+converted into current buffer ----
    buf[wb          ] = pkbf(r0.x, r1.x);
    buf[wb +     SDW] = pkbf(r0.y, r1.y);
    buf[wb + 2 * SDW] = pkbf(r0.z, r1.z);
    buf[wb + 3 * SDW] = pkbf(r0.w, r1.w);

    // ---- degrees (exact fp32) ----
    dacc0 += r0.x + r1.x;
    dacc1 += r0.y + r1.y;
    dacc2 += r0.z + r1.z;
    dacc3 += r0.w + r1.w;

    // ---- prefetch next tile (dummy re-read on last iter) ----
    const float* anext = (it + 1 < KITERS) ? (aptr + (size_t)BKc * Mc) : aptr;
    float4 s0 = *(const float4*)anext;
    float4 s1 = *(const float4*)(anext + Mc);

    // ---- B fragments (bf16, from ws.X — L2/L3 resident) ----
    union { uint4 u; bf16x8 v; } B0, B1;
    B0.u = xq[it * 8];
    B1.u = xq[it * 8 + 4];

    __syncthreads();   // single drain per iter; buffers alternate

    // ---- MFMA: 2 m-tiles x 2 k-steps ----
    const unsigned int* bufc = buf;
    bf16x8 a00 = *(const bf16x8*)(bufc + aaddr[0][0]);
    bf16x8 a10 = *(const bf16x8*)(bufc + aaddr[1][0]);
    acc0 = __builtin_amdgcn_mfma_f32_16x16x32_bf16(a00, B0.v, acc0, 0, 0, 0);
    acc1 = __builtin_amdgcn_mfma_f32_16x16x32_bf16(a10, B0.v, acc1, 0, 0, 0);
    bf16x8 a01 = *(const bf16x8*)(bufc + aaddr[0][1]);
    bf16x8 a11 = *(const bf16x8*)(bufc + aaddr[1][1]);
    acc0 = __builtin_amdgcn_mfma_f32_16x16x32_bf16(a01, B1.v, acc0, 0, 0, 0);
    acc1 = __builtin_amdgcn_mfma_f32_16x16x32_bf16(a11, B1.v, acc1, 0, 0, 0);

    aptr = anext;
    r0 = s0;
    r1 = s1;
  }

  // ---- degree partial reduction + store ----
  __syncthreads();
  atomicAdd(&degs[sm0 + 0], dacc0);
  atomicAdd(&degs[sm0 + 1], dacc1);
  atomicAdd(&degs[sm0 + 2], dacc2);
  atomicAdd(&degs[sm0 + 3], dacc3);
  __syncthreads();
  if (t < BMc)
    D[(size_t)ns * WS_D_FLOATS + bz * Mc + m_base + t] = degs[t];

  // ---- numerator partial store (D layout: col c = l&15, row m = l4*4 + r) ----
#pragma unroll
  for (int tm = 0; tm < 2; ++tm) {
    const f32x4 acc = tm ? acc1 : acc0;
#pragma unroll
    for (int r = 0; r < 4; ++r) {
      const int ml   = tm * 16 + (l4 << 2) + r;
      const size_t o = (size_t)ns * WS_P_FLOATS +
                       ((size_t)(bz * Mc + m_base + ml)) * Cc + (c_b + l15);
      P[o] = acc[r];
    }
  }
}

// ---- kernel 3: combine halves + normalize ----
__global__ __launch_bounds__(256) void fin_kernel(const float* __restrict__ P,
                                                  const float* __restrict__ D,
                                                  float* __restrict__ out) {
  const int g = blockIdx.x * 256 + threadIdx.x;
  const int e = g * 4;
  const int bm = e >> 6;                 // bz*2048 + m
  const float d   = D[bm] + D[WS_D_FLOATS + bm];
  const float inv = 1.0f / fmaxf(d, 1.0f);
  float4 p0 = *(const float4*)(P + e);
  float4 p1 = *(const float4*)(P + WS_P_FLOATS + e);
  float4 o;
  o.x = (p0.x + p1.x) * inv;
  o.y = (p0.y + p1.y) * inv;
  o.z = (p0.z + p1.z) * inv;
  o.w = (p0.w + p1.w) * inv;
  *(float4*)(out + e) = o;
}

extern "C" void kernel_launch(void* const* d_in, const int* in_sizes, int n_in,
                              void* d_out, int out_size, void* d_ws, size_t ws_size,
                              hipStream_t stream) {
  const float* x   = (const float*)d_in[0];  // (8,64,64,64) fp32
  const float* adj = (const float*)d_in[1];  // (8,4096,2048) fp32
  float* out       = (float*)d_out;          // (8,2048,64) fp32
  (void)in_sizes; (void)n_in; (void)out_size; (void)ws_size;

  unsigned int* wsX = (unsigned int*)d_ws;
  float*        wsF = (float*)d_ws;
  float*        P   = wsF + WS_P_OFF;
  float*        D   = wsF + WS_D_OFF;

  // 1) x -> bf16 (2M elems / 8 per thread / 256 per block = 1024 blocks)
  xcvt_kernel<<<dim3(1024), dim3(256), 0, stream>>>(x, wsX);
  // 2) main: 8 bz * 64 m-blocks * 2 N-halves = 1024 blocks (4/CU)
  sgkg_main<<<dim3(BZc * (Mc / BMc) * NSPLIT), dim3(256), 0, stream>>>(wsX, adj, P, D);
  // 3) combine + normalize (2^20 floats / 4 / 256 = 1024 blocks)
  fin_kernel<<<dim3(1024), dim3(256), 0, stream>>>(P, D, out);
}